// Round 1
// 1644.060 us; speedup vs baseline: 2.1039x; 2.1039x over previous
//
#include <hip/hip_runtime.h>
#include <stdint.h>

#define D_  480
#define H_  360
#define W_  32
#define N_  200000
#define DO_ 240
#define HO_ 180
#define WO_ 16
#define NCELL (DO_*HO_*WO_)     // 691,200
#define NVOX  (D_*H_*W_)        // 5,529,600
#define HBITS 19
#define HSZ   (1<<HBITS)
#define HMASK (HSZ-1)

// fallback persistent pool constants
#define PBZ_CELLS 32768
#define POOL_BLOCKS 512
#define POOL_WAVES (POOL_BLOCKS*4)
#define PB_PER_WAVE (PBZ_CELLS/POOL_WAVES)   // 16

__device__ __forceinline__ float bf2f(uint16_t u){
  uint32_t x=((uint32_t)u)<<16; return __builtin_bit_cast(float,x);
}
__device__ __forceinline__ uint16_t f2bf(float f){
  uint32_t x=__builtin_bit_cast(uint32_t,f);
  uint32_t r=x+0x7fffu+((x>>16)&1u);          // RNE
  return (uint16_t)(r>>16);
}
template<bool F32> __device__ __forceinline__ float ldv(const void* p,size_t i){
  if constexpr(F32) return ((const float*)p)[i];
  else return bf2f(((const uint16_t*)p)[i]);
}
template<bool F32> __device__ __forceinline__ void stv(void* p,size_t i,float v){
  if constexpr(F32) ((float*)p)[i]=v;
  else ((uint16_t*)p)[i]=f2bf(v);
}
// broadcast-load 8 consecutive values (16B/32B) -> f32[8]
template<bool F32> __device__ __forceinline__ void ld8(const void* p,size_t base,float* v){
  if constexpr(F32){
    const float4* q=(const float4*)((const float*)p+base);
    float4 a=q[0], b=q[1];
    v[0]=a.x;v[1]=a.y;v[2]=a.z;v[3]=a.w;
    v[4]=b.x;v[5]=b.y;v[6]=b.z;v[7]=b.w;
  }else{
    const uint4* q=(const uint4*)((const uint16_t*)p+base);
    uint4 a=q[0];
    v[0]=bf2f((uint16_t)(a.x&0xffffu)); v[1]=bf2f((uint16_t)(a.x>>16));
    v[2]=bf2f((uint16_t)(a.y&0xffffu)); v[3]=bf2f((uint16_t)(a.y>>16));
    v[4]=bf2f((uint16_t)(a.z&0xffffu)); v[5]=bf2f((uint16_t)(a.z>>16));
    v[6]=bf2f((uint16_t)(a.w&0xffffu)); v[7]=bf2f((uint16_t)(a.w>>16));
  }
}

__device__ __forceinline__ uint32_t hash0(int lin){
  return ((uint32_t)((uint32_t)lin*2654435761u)>>12)&HMASK;
}
__device__ __forceinline__ int hlookup(const int2* __restrict__ h,int lin){
  uint32_t s=hash0(lin);
  for(;;){ int2 kv=h[s]; if(kv.x==lin) return kv.y; if(kv.x<0) return -1; s=(s+1)&HMASK; }
}

// dtype sniff: flag[0]=1 iff inputs are f32. Also zeroes flag[1] (barrier cnt).
__global__ void k_sniff(const uint16_t* __restrict__ feats,int* __restrict__ flag){
  __shared__ int s;
  if(threadIdx.x==0) s=0;
  __syncthreads();
  int bad=0;
  for(int i=threadIdx.x;i<512;i+=256){
    int e=(feats[i]>>7)&0xff;
    bad += (e>=0x90)?1:0;
  }
  atomicAdd(&s,bad);
  __syncthreads();
  if(threadIdx.x==0){ flag[0]=(s>=8)?1:0; flag[1]=0; }
}

// ---------------- dense direct-index voxel table ----------------
__global__ void k_table_init(int* __restrict__ t){
  int i=blockIdx.x*256+threadIdx.x;
  if(i<NVOX/4) ((int4*)t)[i]=make_int4(-1,-1,-1,-1);
}
__global__ void k_table_build(const int4* __restrict__ coords,int* __restrict__ t){
  int i=blockIdx.x*256+threadIdx.x;
  if(i>=N_) return;
  int4 c=coords[i];                      // (b,z,y,x), b==0
  t[(c.y*H_+c.z)*W_+c.w]=i;
}

// ---------------- legacy hash (fallback path only) ----------------
__global__ void k_hash_init(int2* __restrict__ h){
  int i=blockIdx.x*256+threadIdx.x;
  if(i<HSZ) h[i]=make_int2(-1,-1);
}
__global__ void k_hash_build(const int4* __restrict__ coords,int2* __restrict__ h){
  int i=blockIdx.x*256+threadIdx.x;
  if(i>=N_) return;
  int4 c=coords[i];
  int lin=(c.y*H_+c.z)*W_+c.w;
  uint32_t s=hash0(lin);
  for(;;){
    int old=atomicCAS(&h[s].x,-1,lin);
    if(old==-1){ h[s].y=i; break; }
    s=(s+1)&HMASK;
  }
}

// =================================================================
// MAIN PATH: dense table + lane-parallel gather
// =================================================================

// subm conv: one voxel per wave, lane = out channel.
// Lookup: lanes 0..8 probe the 9 offsets in ONE parallel round, ballot+shfl
// compacts hits; dot phase uses all 64 lanes (lane = cout).
// SRC: 0=feats(input dtype) 1=buf0(bf16).  DST: 0=buf0 1=buf1 2=rA(out dtype)
template<int CIN,bool AXIS31,int SRC,int DST,bool RESID,bool F32>
__device__ __forceinline__ void convd_body(const void* __restrict__ feats,
                                           const int4* __restrict__ coords,
                                           const int* __restrict__ table,
                                           const void* __restrict__ Wk,
                                           char* __restrict__ ob,
                                           uint16_t* __restrict__ buf0){
  constexpr size_t ESZ=F32?4:2;
  uint16_t* buf1=buf0+(size_t)N_*64;
  int wave=blockIdx.x*4+(threadIdx.x>>6);
  int lane=threadIdx.x&63;
  if(wave>=N_) return;
  int4 c=coords[wave];
  int z=c.y,y=c.z,x=c.w;
  int nidx=-1;
  if(lane<9){
    int d0=lane/3-1, dxo=lane%3-1;
    int nz=AXIS31? z+d0:z;
    int ny=AXIS31? y:y+d0;
    int nx=x+dxo;
    if(nz>=0&&nz<D_&&ny>=0&&ny<H_&&nx>=0&&nx<W_)
      nidx=table[(nz*H_+ny)*W_+nx];
  }
  unsigned long long m=__ballot(nidx>=0);
  float acc=0.f;
  while(m){
    int k=__builtin_ctzll(m); m&=m-1;       // ascending k: same FP order as ref
    int idx=__shfl(nidx,k);
    size_t fb=(size_t)idx*CIN;
    size_t wb=(size_t)k*CIN*64+lane;
    #pragma unroll
    for(int g=0;g<CIN/8;g++){
      float f[8];
      if(SRC==0) ld8<F32  >(feats,fb+(size_t)8*g,f);
      else       ld8<false>(buf0 ,fb+(size_t)8*g,f);
      #pragma unroll
      for(int j=0;j<8;j++)
        acc+=f[j]*ldv<F32>(Wk,wb+(size_t)(8*g+j)*64);
    }
  }
  float v=acc>0.f? acc:0.01f*acc;
  if(RESID) v+=bf2f(buf1[(size_t)wave*64+lane]);
  size_t oi=(size_t)wave*64+lane;
  if(DST==0)      buf0[oi]=f2bf(v);
  else if(DST==1) buf1[oi]=f2bf(v);
  else            stv<F32>(ob+(size_t)NCELL*64*ESZ,oi,v);
}

template<int CIN,bool AXIS31,int SRC,int DST,bool RESID>
__global__ __launch_bounds__(256)
void k_convd(const void* feats,const int4* coords,const int* table,const void* Wk,
             char* ob,uint16_t* buf0,const int* flag){
  if(flag[0]) convd_body<CIN,AXIS31,SRC,DST,RESID,true >(feats,coords,table,Wk,ob,buf0);
  else        convd_body<CIN,AXIS31,SRC,DST,RESID,false>(feats,coords,table,Wk,ob,buf0);
}

// pool: TWO cells per wave. Lanes 0..26 gather cell A's 27 neighbors,
// lanes 32..58 cell B's, in one parallel round. Dot phase: all 64 lanes
// (lane = cout) over the compacted hit list, ascending k.
template<bool F32>
__device__ __forceinline__ void poold_body(const int* __restrict__ table,
                                           const void* __restrict__ Wp,
                                           char* __restrict__ ob){
  constexpr size_t ESZ=F32?4:2;
  const char* rA=ob+(size_t)NCELL*64*ESZ;
  int wave=blockIdx.x*4+(threadIdx.x>>6);
  int lane=threadIdx.x&63;
  int cell0=wave*2;
  if(cell0>=NCELL) return;
  int half=lane>>5, l=lane&31;
  int cell=cell0+half;
  int ox=cell&(WO_-1);
  int t=cell>>4;                 // WO_ == 16
  int oy=t%HO_, oz=t/HO_;
  int nidx=-1;
  if(l<27){
    int kd=l/9, kh=(l/3)%3, kw=l%3;
    int z=2*oz+kd-1, y=2*oy+kh-1, x=2*ox+kw-1;
    if(z>=0&&z<D_&&y>=0&&y<H_&&x>=0&&x<W_)
      nidx=table[(z*H_+y)*W_+x];
  }
  unsigned long long m=__ballot(nidx>=0);
  float acc0=0.f, acc1=0.f;
  unsigned int ma=(unsigned int)(m&0x07FFFFFFull);
  while(ma){
    int k=__builtin_ctz(ma); ma&=ma-1;
    int idx=__shfl(nidx,k);
    size_t fb=(size_t)idx*64;
    size_t wb=(size_t)k*4096+lane;
    #pragma unroll
    for(int g=0;g<8;g++){
      float f[8]; ld8<F32>(rA,fb+(size_t)8*g,f);
      #pragma unroll
      for(int j=0;j<8;j++)
        acc0+=f[j]*ldv<F32>(Wp,wb+(size_t)(8*g+j)*64);
    }
  }
  unsigned int mb=(unsigned int)((m>>32)&0x07FFFFFFull);
  while(mb){
    int k=__builtin_ctz(mb); mb&=mb-1;
    int idx=__shfl(nidx,32+k);
    size_t fb=(size_t)idx*64;
    size_t wb=(size_t)k*4096+lane;
    #pragma unroll
    for(int g=0;g<8;g++){
      float f[8]; ld8<F32>(rA,fb+(size_t)8*g,f);
      #pragma unroll
      for(int j=0;j<8;j++)
        acc1+=f[j]*ldv<F32>(Wp,wb+(size_t)(8*g+j)*64);
    }
  }
  stv<F32>(ob,(size_t)cell0*64+lane,acc0);
  stv<F32>(ob,((size_t)cell0+1)*64+lane,acc1);
}
__global__ __launch_bounds__(256)
void k_poold(const int* table,const void* Wp,char* ob,const int* flag){
  if(flag[0]) poold_body<true >(table,Wp,ob);
  else        poold_body<false>(table,Wp,ob);
}

// =================================================================
// FALLBACK PATH (ws too small): legacy hash-based kernels, unchanged
// =================================================================
template<int CIN,bool AXIS31,int SRC,int DST,bool RESID,bool WSBUF,bool F32>
__device__ __forceinline__ void conv_body(const void* __restrict__ feats,
                                          const int4* __restrict__ coords,
                                          const int2* __restrict__ hash,
                                          const void* __restrict__ Wk,
                                          char* __restrict__ ob,
                                          uint16_t* __restrict__ wsbuf0){
  constexpr size_t ESZ=F32?4:2;
  uint16_t* buf0 = WSBUF ? wsbuf0 : (uint16_t*)(ob+(size_t)PBZ_CELLS*64*ESZ);
  uint16_t* buf1 = buf0 + (size_t)N_*64;
  int wave=blockIdx.x*4+(threadIdx.x>>6);
  int lane=threadIdx.x&63;
  if(wave>=N_) return;
  int4 c=coords[wave];
  int z=c.y,y=c.z,x=c.w;
  float acc=0.f;
  #pragma unroll
  for(int k=0;k<9;k++){
    const int d0=k/3-1, dxo=k%3-1;
    int nz=AXIS31? z+d0:z;
    int ny=AXIS31? y:y+d0;
    int nx=x+dxo;
    int nidx=-1;
    if(nz>=0&&nz<D_&&ny>=0&&ny<H_&&nx>=0&&nx<W_)
      nidx=hlookup(hash,(nz*H_+ny)*W_+nx);
    nidx=__builtin_amdgcn_readfirstlane(nidx);
    if(nidx<0) continue;
    size_t fb=(size_t)nidx*CIN;
    size_t wb=(size_t)k*CIN*64+lane;
    #pragma unroll
    for(int ci=0;ci<CIN;ci+=2){
      float f0=(SRC==0)? ldv<F32>(feats,fb+ci)   : bf2f(buf0[fb+ci]);
      float f1=(SRC==0)? ldv<F32>(feats,fb+ci+1) : bf2f(buf0[fb+ci+1]);
      acc += f0*ldv<F32>(Wk,wb+(size_t)ci*64);
      acc += f1*ldv<F32>(Wk,wb+(size_t)(ci+1)*64);
    }
  }
  float v=acc>0.f? acc:0.01f*acc;
  if(RESID) v+=bf2f(buf1[(size_t)wave*64+lane]);
  size_t oi=(size_t)wave*64+lane;
  if(DST==0)      buf0[oi]=f2bf(v);
  else if(DST==1) buf1[oi]=f2bf(v);
  else            stv<F32>(ob+(size_t)NCELL*64*ESZ,oi,v);
}
template<int CIN,bool AXIS31,int SRC,int DST,bool RESID,bool WSBUF>
__global__ __launch_bounds__(256)
void k_conv(const void* feats,const int4* coords,const int2* hash,const void* Wk,
            char* ob,uint16_t* wsbuf0,const int* flag){
  if(flag[0]) conv_body<CIN,AXIS31,SRC,DST,RESID,WSBUF,true >(feats,coords,hash,Wk,ob,wsbuf0);
  else        conv_body<CIN,AXIS31,SRC,DST,RESID,WSBUF,false>(feats,coords,hash,Wk,ob,wsbuf0);
}
template<bool F32>
__device__ __forceinline__ float pool_cell_t(int cell,const void* __restrict__ rA,
    const int2* __restrict__ hash,const void* __restrict__ Wp,int lane){
  int ox=cell&(WO_-1);
  int t=cell>>4;
  int oy=t%HO_, oz=t/HO_;
  float acc=0.f;
  int k=0;
  for(int kd=0;kd<3;kd++)for(int kh=0;kh<3;kh++)for(int kw=0;kw<3;kw++,k++){
    int z=2*oz+kd-1, y=2*oy+kh-1, x=2*ox+kw-1;
    if(z<0||z>=D_||y<0||y>=H_||x<0||x>=W_) continue;
    int nidx=hlookup(hash,(z*H_+y)*W_+x);
    nidx=__builtin_amdgcn_readfirstlane(nidx);
    if(nidx<0) continue;
    size_t fb=(size_t)nidx*64;
    size_t wb=(size_t)k*4096+lane;
    #pragma unroll
    for(int ci=0;ci<64;ci+=2){
      acc+=ldv<F32>(rA,fb+ci)  *ldv<F32>(Wp,wb+(size_t)ci*64);
      acc+=ldv<F32>(rA,fb+ci+1)*ldv<F32>(Wp,wb+(size_t)(ci+1)*64);
    }
  }
  return acc;
}
template<bool F32>
__device__ __forceinline__ void pool_fb_body(const void* __restrict__ Wp,
                                             char* __restrict__ ob,
                                             int* __restrict__ cnt){
  constexpr size_t ESZ=F32?4:2;
  const int2* hash=(const int2*)ob;
  const void* rA=ob+(size_t)NCELL*64*ESZ;
  int w=blockIdx.x*4+(threadIdx.x>>6);
  int lane=threadIdx.x&63;
  for(int cell=PBZ_CELLS+w; cell<NCELL; cell+=POOL_WAVES)
    stv<F32>(ob,(size_t)cell*64+lane, pool_cell_t<F32>(cell,rA,hash,Wp,lane));
  float accb[PB_PER_WAVE];
  #pragma unroll
  for(int j=0;j<PB_PER_WAVE;j++)
    accb[j]=pool_cell_t<F32>(w*PB_PER_WAVE+j,rA,hash,Wp,lane);
  __syncthreads();
  if(threadIdx.x==0){
    __threadfence();
    atomicAdd(cnt,1);
    while(atomicAdd(cnt,0)<POOL_BLOCKS) __builtin_amdgcn_s_sleep(8);
  }
  __syncthreads();
  #pragma unroll
  for(int j=0;j<PB_PER_WAVE;j++)
    stv<F32>(ob,(size_t)(w*PB_PER_WAVE+j)*64+lane,accb[j]);
}
__global__ __launch_bounds__(256,2)
void k_pool_fb(const void* Wp,char* ob,int* cnt,const int* flag){
  if(flag[0]) pool_fb_body<true >(Wp,ob,cnt);
  else        pool_fb_body<false>(Wp,ob,cnt);
}

extern "C" void kernel_launch(void* const* d_in,const int* in_sizes,int n_in,
                              void* d_out,int out_size,void* d_ws,size_t ws_size,
                              hipStream_t stream){
  const uint16_t* feats_u16=(const uint16_t*)d_in[0];
  const void* feats=d_in[0];
  const int4* coords=(const int4*)d_in[1];
  const void* W1  =d_in[2];
  const void* W1_2=d_in[3];
  const void* W2  =d_in[4];
  const void* W3  =d_in[5];
  const void* Wp  =d_in[6];
  char* ob=(char*)d_out;
  int* flag=(int*)d_ws;                       // [0]=is_f32, [1]=barrier cnt

  // main path needs: flag(256) + buf0+buf1 (2 * N * 64 * bf16) = ~51.2 MB
  // (dense table for convs lives in ob's pooled region; for the pool it is
  //  rebuilt over the then-dead buf region in ws -> no aliasing anywhere)
  const size_t WS_NEED = 256 + (size_t)2*N_*64*2;
  const bool ws_ok = ws_size >= WS_NEED;
  uint16_t* buf0_ws=(uint16_t*)((char*)d_ws+256);
  int*      tab_ws =(int*)((char*)d_ws+256);  // 22.1 MB, fits inside buf0 (25.6 MB)
  int*      tab_ob =(int*)ob;                 // 22.1 MB, inside pooled region (>=88.5 MB)

  k_sniff<<<1,256,0,stream>>>(feats_u16,flag);

  if(ws_ok){
    k_table_init <<<NVOX/4/256,256,0,stream>>>(tab_ob);
    k_table_build<<<(N_+255)/256,256,0,stream>>>(coords,tab_ob);
    k_convd<32,true ,0,0,false><<<N_/4,256,0,stream>>>(feats,coords,tab_ob,W1  ,ob,buf0_ws,flag);
    k_convd<64,false,1,1,false><<<N_/4,256,0,stream>>>(feats,coords,tab_ob,W1_2,ob,buf0_ws,flag);
    k_convd<32,false,0,0,false><<<N_/4,256,0,stream>>>(feats,coords,tab_ob,W2  ,ob,buf0_ws,flag);
    k_convd<64,true ,1,2,true ><<<N_/4,256,0,stream>>>(feats,coords,tab_ob,W3  ,ob,buf0_ws,flag);
    // bufs are dead now; rebuild the table in ws so pool writes can't clobber it
    k_table_init <<<NVOX/4/256,256,0,stream>>>(tab_ws);
    k_table_build<<<(N_+255)/256,256,0,stream>>>(coords,tab_ws);
    k_poold<<<NCELL/8,256,0,stream>>>(tab_ws,Wp,ob,flag);
  }else{
    int2* hash=(int2*)ob;
    k_hash_init<<<(HSZ+255)/256,256,0,stream>>>(hash);
    k_hash_build<<<(N_+255)/256,256,0,stream>>>(coords,hash);
    k_conv<32,true ,0,0,false,false><<<N_/4,256,0,stream>>>(feats,coords,hash,W1  ,ob,nullptr,flag);
    k_conv<64,false,1,1,false,false><<<N_/4,256,0,stream>>>(feats,coords,hash,W1_2,ob,nullptr,flag);
    k_conv<32,false,0,0,false,false><<<N_/4,256,0,stream>>>(feats,coords,hash,W2  ,ob,nullptr,flag);
    k_conv<64,true ,1,2,true ,false><<<N_/4,256,0,stream>>>(feats,coords,hash,W3  ,ob,nullptr,flag);
    k_pool_fb<<<POOL_BLOCKS,256,0,stream>>>(Wp,ob,flag+1,flag);
  }
}